// Round 12
// baseline (274.302 us; speedup 1.0000x reference)
//
#include <hip/hip_runtime.h>
#include <math.h>

#define N_ATOMS 50000
#define IN_DIM 128
#define HID 256
#define N_ELEM 4
#define N_IMG 500
#define NNZ 2000000

typedef __attribute__((ext_vector_type(8))) short bf16x8;   // 8 bf16 = 4 VGPRs
typedef __attribute__((ext_vector_type(4))) float f32x4;    // MFMA C/D frag
typedef __attribute__((ext_vector_type(4))) int   i32x4;    // native vec for NT loads
typedef __attribute__((ext_vector_type(4))) float fv4;      // native vec for NT loads

__device__ __forceinline__ int elem_of(int z) {
    return (z == 1) ? 0 : (z == 6) ? 1 : (z == 8) ? 2 : 3;
}

__device__ __forceinline__ unsigned short f2bf(float f) {   // RNE
    unsigned u = __float_as_uint(f);
    u += 0x7fffu + ((u >> 16) & 1u);
    return (unsigned short)(u >> 16);
}
__device__ __forceinline__ float bf2f(unsigned short u) {
    return __uint_as_float(((unsigned)u) << 16);
}
__device__ __forceinline__ float tanh_fast(float x) {
    float e = __expf(2.f * x);
    return (e - 1.f) / (e + 1.f);
}

// ---------------------------------------------------------------------------
// 1) Bucket atoms by element — LDS-aggregated. Also zeroes F.
// ---------------------------------------------------------------------------
__global__ __launch_bounds__(256) void bucket_kernel(
    const int* __restrict__ Z, int* __restrict__ counts, int* __restrict__ lists,
    float* __restrict__ F) {
    for (int idx = blockIdx.x * blockDim.x + threadIdx.x; idx < 3 * N_ATOMS;
         idx += gridDim.x * blockDim.x) F[idx] = 0.f;
    __shared__ int lcnt[N_ELEM], lbase[N_ELEM];
    const int i = blockIdx.x * blockDim.x + threadIdx.x;
    if (threadIdx.x < N_ELEM) lcnt[threadIdx.x] = 0;
    __syncthreads();
    int e = -1, pos = 0;
    if (i < N_ATOMS) {
        e = elem_of(Z[i]);
        pos = atomicAdd(&lcnt[e], 1);
    }
    __syncthreads();
    if (threadIdx.x < N_ELEM)
        lbase[threadIdx.x] = atomicAdd(&counts[threadIdx.x], lcnt[threadIdx.x]);
    __syncthreads();
    if (i < N_ATOMS) lists[e * N_ATOMS + lbase[e] + pos] = i;
}

// ---------------------------------------------------------------------------
// 1b) Weight prep — pre-swizzle into wave-frag order (R9: worth 44us).
//     Also zeroes counts (block 0).
// ---------------------------------------------------------------------------
__global__ __launch_bounds__(256) void prep_weights(
    const float* __restrict__ W0, const float* __restrict__ W1,
    unsigned short* __restrict__ W0s1,   // stage1: Bt[h][d], K=128, KN=4
    unsigned short* __restrict__ W1s2,   // stage2: Bt[h1][h0], K=256, KN=8
    unsigned short* __restrict__ W1s3,   // stage3: Bt[h0][h1], K=256, KN=8
    unsigned short* __restrict__ W0s4,   // stage4: Bt[d][h], K=256, KN=8
    int* __restrict__ counts) {
    if (blockIdx.x == 0 && threadIdx.x < N_ELEM) counts[threadIdx.x] = 0;
    int t = blockIdx.x * 256 + threadIdx.x;
    if (t >= N_ELEM * HID * HID) return;
    int e = t >> 16;
    int rem = t & 65535;
    int k = rem >> 8, n = rem & 255;     // W1[e][k=h0][n=h1]
    unsigned short w1 = f2bf(W1[t]);
    {   // stage2: row = n (h1), col = k (h0)
        int lane = (((k >> 3) & 3) << 4) | (n & 15);
        W1s2[(e << 16) + ((((n >> 4) * 8 + (k >> 5)) * 64 + lane) << 3) + (k & 7)] = w1;
    }
    {   // stage3: row = k (h0), col = n (h1)
        int lane = (((n >> 3) & 3) << 4) | (k & 15);
        W1s3[(e << 16) + ((((k >> 4) * 8 + (n >> 5)) * 64 + lane) << 3) + (n & 7)] = w1;
    }
    if (k < IN_DIM) {                    // W0[e][d=k][h=n]
        unsigned short w0 = f2bf(W0[e * (IN_DIM * HID) + rem]);
        {   // stage1: row = n (h), col = k (d), K=128 -> KN=4
            int lane = (((k >> 3) & 3) << 4) | (n & 15);
            W0s1[e * (IN_DIM * HID) + ((((n >> 4) * 4 + (k >> 5)) * 64 + lane) << 3) + (k & 7)] = w0;
        }
        {   // stage4: row = k (d), col = n (h), K=256 -> KN=8
            int lane = (((n >> 3) & 3) << 4) | (k & 15);
            W0s4[e * (IN_DIM * HID) + ((((k >> 4) * 8 + (n >> 5)) * 64 + lane) << 3) + (n & 7)] = w0;
        }
    }
}

// ---------------------------------------------------------------------------
// 2) FULLY-FUSED MLP fwd+bwd. R10 post-mortem: ring-3 prefetch was neutral ->
//    not latency-bound but L2-CAPACITY bound: grid (MT,1,4) mixes all 4
//    elements' blocks on every XCD (~6 MB hot weights vs 4 MB L2). Fix:
//    1-D grid with XCD-pinned elements — assuming round-robin XCD =
//    blockIdx%8 (perf-only heuristic), e = (bid&7)&3 makes each XCD serve
//    ONE element; its 1.5 MB weight set fits L2 fully. 512 tiles/element
//    (16384-atom headroom, >> +40 sigma of the binomial element count).
//    Everything else unchanged from R10 (swizzled coalesced B loads, ring
//    prefetch, barrier-free K-loops, 35 KB LDS -> 4 blocks/CU).
// ---------------------------------------------------------------------------
#define TILES_PER_E 512   // covers cnt up to 16384 per element
__global__ __launch_bounds__(256, 4) void fused_mlp(
    const float* __restrict__ fp,
    const unsigned short* __restrict__ W0s1,
    const unsigned short* __restrict__ W1s2,
    const unsigned short* __restrict__ W1s3,
    const unsigned short* __restrict__ W0s4,
    const float* __restrict__ b0, const float* __restrict__ b1,
    const float* __restrict__ W2, const float* __restrict__ b2,
    float* __restrict__ o_atom,
    unsigned short* __restrict__ Gb,
    const int* __restrict__ counts, const int* __restrict__ lists) {

    const int bid = blockIdx.x;
    const int xcd = bid & 7;
    const int e = xcd & 3;                       // element pinned to XCD pair
    const int tile = (bid >> 3) * 2 + (xcd >> 2);
    const int cnt = counts[e];
    const int m0 = tile * 32;
    if (m0 >= cnt) return;
    const int* list = lists + e * N_ATOMS;

    __shared__ short tH[8 * 32 * 34];      // 17408 B
    __shared__ short tD[8 * 32 * 34];      // 17408 B
    __shared__ float red[4][32];           // 512 B   (total 35328 B)

    const int tid = threadIdx.x;
    const int lane = tid & 63;
    const int wv = tid >> 6;       // 0..3, n-range wv*64
    const int lr = lane & 15;
    const int lq = lane >> 4;

    const unsigned short* B1 = W0s1 + (size_t)e * HID * IN_DIM;
    const unsigned short* B2 = W1s2 + (size_t)e * HID * HID;
    const unsigned short* B3 = W1s3 + (size_t)e * HID * HID;
    const unsigned short* B4 = W0s4 + (size_t)e * IN_DIM * HID;

    // A-row pointers for the 2 m-tiles (rows mt*16 + lr)
    const float* arow[2];
    bool aok[2];
#pragma unroll
    for (int mt = 0; mt < 2; ++mt) {
        int m = m0 + mt * 16 + lr;
        aok[mt] = (m < cnt);
        arow[mt] = aok[mt] ? (fp + (size_t)list[m] * IN_DIM) : fp;
    }

    f32x4 acc[2][4];
#define ZERO_ACC()                                                        \
    _Pragma("unroll") for (int mt = 0; mt < 2; ++mt)                      \
        _Pragma("unroll") for (int nt = 0; nt < 4; ++nt)                  \
            _Pragma("unroll") for (int j = 0; j < 4; ++j) acc[mt][nt][j] = 0.f;

    // =============== Stage 1: z0 = fp @ W0^T   (K=128, KN=4, ring-2) ======
    ZERO_ACC();
    {
        float4 a0[2][2], a1[2][2];
        bf16x8 bb[2][4];
#pragma unroll
        for (int mt = 0; mt < 2; ++mt) if (aok[mt]) {
            a0[0][mt] = *(const float4*)(arow[mt] + lq * 8);
            a1[0][mt] = *(const float4*)(arow[mt] + lq * 8 + 4);
        }
#pragma unroll
        for (int nt = 0; nt < 4; ++nt)
            bb[0][nt] = *(const bf16x8*)(B1 +
                ((size_t)(((wv * 4 + nt) * 4 + 0) * 64 + lane) << 3));
#pragma unroll
        for (int ki = 0; ki < 4; ++ki) {
            const int cur = ki & 1, nx = cur ^ 1;
            if (ki < 3) {
                const int k0n = (ki + 1) * 32;
#pragma unroll
                for (int mt = 0; mt < 2; ++mt) if (aok[mt]) {
                    a0[nx][mt] = *(const float4*)(arow[mt] + k0n + lq * 8);
                    a1[nx][mt] = *(const float4*)(arow[mt] + k0n + lq * 8 + 4);
                }
#pragma unroll
                for (int nt = 0; nt < 4; ++nt)
                    bb[nx][nt] = *(const bf16x8*)(B1 +
                        ((size_t)(((wv * 4 + nt) * 4 + ki + 1) * 64 + lane) << 3));
            }
            bf16x8 af[2];
#pragma unroll
            for (int mt = 0; mt < 2; ++mt) {
                bf16x8 v;
#pragma unroll
                for (int j = 0; j < 8; ++j) v[j] = 0;
                if (aok[mt]) {
                    v[0] = (short)f2bf(a0[cur][mt].x); v[1] = (short)f2bf(a0[cur][mt].y);
                    v[2] = (short)f2bf(a0[cur][mt].z); v[3] = (short)f2bf(a0[cur][mt].w);
                    v[4] = (short)f2bf(a1[cur][mt].x); v[5] = (short)f2bf(a1[cur][mt].y);
                    v[6] = (short)f2bf(a1[cur][mt].z); v[7] = (short)f2bf(a1[cur][mt].w);
                }
                af[mt] = v;
            }
#pragma unroll
            for (int mt = 0; mt < 2; ++mt)
#pragma unroll
                for (int nt = 0; nt < 4; ++nt)
                    acc[mt][nt] = __builtin_amdgcn_mfma_f32_16x16x32_bf16(
                        af[mt], bb[cur][nt], acc[mt][nt], 0, 0, 0);
        }
    }

    // S2 B-ring preload (hoisted: flies during epilogue-1 VALU + barrier)
    bf16x8 b2r[3][4];
#pragma unroll
    for (int p = 0; p < 3; ++p)
#pragma unroll
        for (int nt = 0; nt < 4; ++nt)
            b2r[p][nt] = *(const bf16x8*)(B2 +
                ((size_t)(((wv * 4 + nt) * 8 + p) * 64 + lane) << 3));

    // epilogue 1: h0 -> tH
    {
        float bv[4];
#pragma unroll
        for (int nt = 0; nt < 4; ++nt)
            bv[nt] = b0[e * HID + wv * 64 + nt * 16 + lr];
#pragma unroll
        for (int mt = 0; mt < 2; ++mt)
#pragma unroll
            for (int r = 0; r < 4; ++r) {
                const int row = mt * 16 + lq * 4 + r;
#pragma unroll
                for (int nt = 0; nt < 4; ++nt) {
                    const int n = wv * 64 + nt * 16 + lr;
                    float t = tanh_fast(acc[mt][nt][r] + bv[nt]);
                    tH[(n >> 5) * 1088 + row * 34 + (n & 31)] = (short)f2bf(t);
                }
            }
    }
    __syncthreads();

    // =============== Stage 2: z1 = h0 @ W1^T   (K=256, ring-3) =============
    ZERO_ACC();
#pragma unroll
    for (int ki = 0; ki < 8; ++ki) {
        bf16x8 af[2];
#pragma unroll
        for (int mt = 0; mt < 2; ++mt)
            af[mt] = *(const bf16x8*)&tH[ki * 1088 + (mt * 16 + lr) * 34 + lq * 8];
#pragma unroll
        for (int mt = 0; mt < 2; ++mt)
#pragma unroll
            for (int nt = 0; nt < 4; ++nt)
                acc[mt][nt] = __builtin_amdgcn_mfma_f32_16x16x32_bf16(
                    af[mt], b2r[ki % 3][nt], acc[mt][nt], 0, 0, 0);
        if (ki < 5) {
#pragma unroll
            for (int nt = 0; nt < 4; ++nt)
                b2r[ki % 3][nt] = *(const bf16x8*)(B2 +
                    ((size_t)(((wv * 4 + nt) * 8 + ki + 3) * 64 + lane) << 3));
        }
    }

    // S3 B-ring preload (hoisted above epilogue-2 + barrier)
    bf16x8 b3r[3][4];
#pragma unroll
    for (int p = 0; p < 3; ++p)
#pragma unroll
        for (int nt = 0; nt < 4; ++nt)
            b3r[p][nt] = *(const bf16x8*)(B3 +
                ((size_t)(((wv * 4 + nt) * 8 + p) * 64 + lane) << 3));

    // epilogue 2: dz1 -> tD; o partials -> red
    {
        float bv[4], w2v[4];
#pragma unroll
        for (int nt = 0; nt < 4; ++nt) {
            bv[nt]  = b1[e * HID + wv * 64 + nt * 16 + lr];
            w2v[nt] = W2[e * HID + wv * 64 + nt * 16 + lr];
        }
#pragma unroll
        for (int mt = 0; mt < 2; ++mt)
#pragma unroll
            for (int r = 0; r < 4; ++r) {
                const int row = mt * 16 + lq * 4 + r;
                float osum = 0.f;
#pragma unroll
                for (int nt = 0; nt < 4; ++nt) {
                    const int n = wv * 64 + nt * 16 + lr;
                    float t = tanh_fast(acc[mt][nt][r] + bv[nt]);
                    osum += t * w2v[nt];
                    tD[(n >> 5) * 1088 + row * 34 + (n & 31)] =
                        (short)f2bf(w2v[nt] * (1.f - t * t));
                }
                osum += __shfl_xor(osum, 1, 64);
                osum += __shfl_xor(osum, 2, 64);
                osum += __shfl_xor(osum, 4, 64);
                osum += __shfl_xor(osum, 8, 64);
                if (lr == 0) red[wv][row] = osum;
            }
    }
    __syncthreads();
    if (tid < 32) {
        int m = m0 + tid;
        if (m < cnt)
            o_atom[list[m]] = red[0][tid] + red[1][tid] + red[2][tid] +
                              red[3][tid] + b2[e];
    }

    // =============== Stage 3: dh0 = dz1 @ W1   (K=256, ring-3) =============
    ZERO_ACC();
#pragma unroll
    for (int ki = 0; ki < 8; ++ki) {
        bf16x8 af[2];
#pragma unroll
        for (int mt = 0; mt < 2; ++mt)
            af[mt] = *(const bf16x8*)&tD[ki * 1088 + (mt * 16 + lr) * 34 + lq * 8];
#pragma unroll
        for (int mt = 0; mt < 2; ++mt)
#pragma unroll
            for (int nt = 0; nt < 4; ++nt)
                acc[mt][nt] = __builtin_amdgcn_mfma_f32_16x16x32_bf16(
                    af[mt], b3r[ki % 3][nt], acc[mt][nt], 0, 0, 0);
        if (ki < 5) {
#pragma unroll
            for (int nt = 0; nt < 4; ++nt)
                b3r[ki % 3][nt] = *(const bf16x8*)(B3 +
                    ((size_t)(((wv * 4 + nt) * 8 + ki + 3) * 64 + lane) << 3));
        }
    }

    // S4 B-ring preload (hoisted above epilogue-3 + barrier)
    bf16x8 b4r[3][2];
#pragma unroll
    for (int p = 0; p < 3; ++p)
#pragma unroll
        for (int nt = 0; nt < 2; ++nt)
            b4r[p][nt] = *(const bf16x8*)(B4 +
                ((size_t)(((wv * 2 + nt) * 8 + p) * 64 + lane) << 3));

    // epilogue 3: dz0 = dh0*(1-h0^2) -> tH in-place (same thread owns slot)
#pragma unroll
    for (int mt = 0; mt < 2; ++mt)
#pragma unroll
        for (int r = 0; r < 4; ++r) {
            const int row = mt * 16 + lq * 4 + r;
#pragma unroll
            for (int nt = 0; nt < 4; ++nt) {
                const int n = wv * 64 + nt * 16 + lr;
                const int a = (n >> 5) * 1088 + row * 34 + (n & 31);
                float h = bf2f((unsigned short)tH[a]);
                tH[a] = (short)f2bf(acc[mt][nt][r] * (1.f - h * h));
            }
        }
    __syncthreads();

    // =============== Stage 4: g = dz0 @ W0   (K=256, NT=2, ring-3) =========
    {
        f32x4 a4[2][2];
#pragma unroll
        for (int mt = 0; mt < 2; ++mt)
#pragma unroll
            for (int nt = 0; nt < 2; ++nt)
#pragma unroll
                for (int j = 0; j < 4; ++j) a4[mt][nt][j] = 0.f;
#pragma unroll
        for (int ki = 0; ki < 8; ++ki) {
            bf16x8 af[2];
#pragma unroll
            for (int mt = 0; mt < 2; ++mt)
                af[mt] = *(const bf16x8*)&tH[ki * 1088 + (mt * 16 + lr) * 34 + lq * 8];
#pragma unroll
            for (int mt = 0; mt < 2; ++mt)
#pragma unroll
                for (int nt = 0; nt < 2; ++nt)
                    a4[mt][nt] = __builtin_amdgcn_mfma_f32_16x16x32_bf16(
                        af[mt], b4r[ki % 3][nt], a4[mt][nt], 0, 0, 0);
            if (ki < 5) {
#pragma unroll
                for (int nt = 0; nt < 2; ++nt)
                    b4r[ki % 3][nt] = *(const bf16x8*)(B4 +
                        ((size_t)(((wv * 2 + nt) * 8 + ki + 3) * 64 + lane) << 3));
            }
        }
        // epilogue 4: g -> tD chunk-major, then coalesced bf16x8 scatter
#pragma unroll
        for (int mt = 0; mt < 2; ++mt)
#pragma unroll
            for (int r = 0; r < 4; ++r) {
                const int row = mt * 16 + lq * 4 + r;
#pragma unroll
                for (int nt = 0; nt < 2; ++nt) {
                    const int n = wv * 32 + nt * 16 + lr;
                    tD[(n >> 5) * 1088 + row * 34 + (n & 31)] =
                        (short)f2bf(a4[mt][nt][r]);
                }
            }
    }
    __syncthreads();
#pragma unroll
    for (int t = 0; t < 2; ++t) {
        const int c = tid + 256 * t;         // 0..511
        const int row = c >> 4;              // 0..31
        const int pos = (c & 15) * 8;        // 0..120
        const int m = m0 + row;
        if (m < cnt) {
            bf16x8 v = *(const bf16x8*)&tD[(pos >> 5) * 1088 + row * 34 + (pos & 31)];
            *(bf16x8*)(Gb + (size_t)list[m] * IN_DIM + pos) = v;
        }
    }
#undef ZERO_ACC
}

// ---------------------------------------------------------------------------
// 3) Forces + energy fused. R10 post-mortem: rows/cols/vals are single-use
//    24 MB streams that evict the 12.8 MB g-gather footprint from L2 ->
//    nontemporal loads (native ext_vector types — HIP int4/float4 wrappers
//    don't compile with the builtin) keep g resident. Blocks < N_IMG also
//    reduce their image's energy.
// ---------------------------------------------------------------------------
__global__ __launch_bounds__(256) void forces_kernel(
    const int* __restrict__ rows, const int* __restrict__ cols,
    const float* __restrict__ vals, const unsigned short* __restrict__ g,
    float* __restrict__ F,
    const float* __restrict__ o_atom, const int* __restrict__ img,
    float* __restrict__ energy) {
    const int i0 = (blockIdx.x * 256 + threadIdx.x) * 4;
    if (i0 < NNZ) {
        i32x4 r = __builtin_nontemporal_load((const i32x4*)(rows + i0));
        i32x4 c = __builtin_nontemporal_load((const i32x4*)(cols + i0));
        fv4   v = __builtin_nontemporal_load((const fv4*)(vals + i0));
        float g0 = bf2f(g[r[0]]), g1 = bf2f(g[r[1]]);
        float g2 = bf2f(g[r[2]]), g3 = bf2f(g[r[3]]);
        atomicAdd(&F[c[0]], -v[0] * g0);
        atomicAdd(&F[c[1]], -v[1] * g1);
        atomicAdd(&F[c[2]], -v[2] * g2);
        atomicAdd(&F[c[3]], -v[3] * g3);
    }
    if (blockIdx.x < N_IMG) {
        const int b = blockIdx.x;
        int lo, hi;
        {
            int l = 0, r = N_ATOMS;
            while (l < r) { int m = (l + r) >> 1; if (img[m] < b) l = m + 1; else r = m; }
            lo = l;
        }
        {
            int l = lo, r = N_ATOMS;
            while (l < r) { int m = (l + r) >> 1; if (img[m] < b + 1) l = m + 1; else r = m; }
            hi = l;
        }
        float s = 0.f;
        for (int i = lo + (int)threadIdx.x; i < hi; i += 256) s += o_atom[i];
#pragma unroll
        for (int off = 32; off > 0; off >>= 1) s += __shfl_down(s, off, 64);
        __shared__ float red[4];
        if ((threadIdx.x & 63) == 0) red[threadIdx.x >> 6] = s;
        __syncthreads();
        if (threadIdx.x == 0) energy[b] = red[0] + red[1] + red[2] + red[3];
    }
}

// ---------------------------------------------------------------------------
extern "C" void kernel_launch(void* const* d_in, const int* in_sizes, int n_in,
                              void* d_out, int out_size, void* d_ws, size_t ws_size,
                              hipStream_t stream) {
    const float* fp    = (const float*)d_in[0];
    const int*   Z     = (const int*)d_in[1];
    const int*   img   = (const int*)d_in[2];
    const int*   frows = (const int*)d_in[3];
    const int*   fcols = (const int*)d_in[4];
    const float* fvals = (const float*)d_in[5];
    const float* W0    = (const float*)d_in[6];
    const float* b0    = (const float*)d_in[7];
    const float* W1    = (const float*)d_in[8];
    const float* b1    = (const float*)d_in[9];
    const float* W2    = (const float*)d_in[10];
    const float* b2    = (const float*)d_in[11];

    float* out    = (float*)d_out;
    float* energy = out;             // [N_IMG]
    float* F      = out + N_IMG;     // [3*N_ATOMS]

    char* ws = (char*)d_ws;
    int*   counts = (int*)ws;                                   // 16 B
    int*   lists  = (int*)(ws + 1024);                          // 800 KB
    char*  base   = ws + (1 << 20);
    unsigned short* Gb   = (unsigned short*)(base);              // 50000*128 bf16 (atom order)
    float* o_atom        = (float*)(base + 13000000);            // 50000 f32
    unsigned short* W0s1 = (unsigned short*)(base + 14000000);   // swizzled, 256 KB
    unsigned short* W0s4 = W0s1 + N_ELEM * IN_DIM * HID;         // swizzled, 256 KB
    unsigned short* W1s2 = W0s4 + N_ELEM * IN_DIM * HID;         // swizzled, 512 KB
    unsigned short* W1s3 = W1s2 + N_ELEM * HID * HID;            // swizzled, 512 KB

    // 4 dispatches: prep(+counts0), bucket(+F0), fused, forces(+energy)
    prep_weights<<<(N_ELEM * HID * HID + 255) / 256, 256, 0, stream>>>(
        W0, W1, W0s1, W1s2, W1s3, W0s4, counts);
    bucket_kernel<<<(N_ATOMS + 255) / 256, 256, 0, stream>>>(Z, counts, lists, F);

    // 1-D grid, XCD-pinned elements: 8 * (TILES_PER_E/2) blocks
    fused_mlp<<<8 * (TILES_PER_E / 2), 256, 0, stream>>>(
        fp, W0s1, W1s2, W1s3, W0s4, b0, b1, W2, b2, o_atom, Gb, counts, lists);

    forces_kernel<<<(NNZ / 4 + 255) / 256, 256, 0, stream>>>(
        frows, fcols, fvals, Gb, F, o_atom, img, energy);
}